// Round 7
// baseline (554.405 us; speedup 1.0000x reference)
//
#include <hip/hip_runtime.h>
#include <hip/hip_fp16.h>
#include <stdint.h>
#include <stddef.h>

typedef _Float16 f16;
typedef _Float16 f16x8 __attribute__((ext_vector_type(8)));
typedef _Float16 f16x4 __attribute__((ext_vector_type(4)));
typedef float    f32x4 __attribute__((ext_vector_type(4)));

#define NB  2
#define NS  2048
#define NDM 1024
#define NH  16
#define ND  64
#define NM  4096   // NB*NS

// ---------------------------------------------------------------------------
// K0a: convert Q/K/V inputs f32 -> f16   (grid: (2048, 3), block 256; 8 elem/thr)
// ---------------------------------------------------------------------------
__global__ __launch_bounds__(256) void cvt_x_kernel(const float* __restrict__ q,
                                                    const float* __restrict__ k,
                                                    const float* __restrict__ v,
                                                    f16* __restrict__ xh)
{
    const float* src = (blockIdx.y == 0) ? q : (blockIdx.y == 1) ? k : v;
    f16* dst = xh + (size_t)blockIdx.y * ((size_t)NM * NDM);
    size_t i = ((size_t)blockIdx.x * 256 + threadIdx.x) * 8;
    float4 a = *(const float4*)(src + i);
    float4 b = *(const float4*)(src + i + 4);
    f16x8 o;
    o[0] = (f16)a.x; o[1] = (f16)a.y; o[2] = (f16)a.z; o[3] = (f16)a.w;
    o[4] = (f16)b.x; o[5] = (f16)b.y; o[6] = (f16)b.z; o[7] = (f16)b.w;
    *(f16x8*)(dst + i) = o;
}

// ---------------------------------------------------------------------------
// K0b: W [K][N] f32 -> Wt [N][K] f16 (transposed, so GEMM B-frags are contiguous)
// grid: (16,16,4), block 256, 64x64 tiles
// ---------------------------------------------------------------------------
__global__ __launch_bounds__(256) void transp_w_kernel(const float* __restrict__ w0,
                                                       const float* __restrict__ w1,
                                                       const float* __restrict__ w2,
                                                       const float* __restrict__ w3,
                                                       f16* __restrict__ wt)
{
    __shared__ float t[64][65];
    const int z = blockIdx.z;
    const float* src = (z==0)?w0:(z==1)?w1:(z==2)?w2:w3;
    f16* dst = wt + (size_t)z * ((size_t)NDM * NDM);
    const int k0 = blockIdx.y * 64, n0 = blockIdx.x * 64;
    const int c = threadIdx.x & 63, r4 = threadIdx.x >> 6;
    #pragma unroll
    for (int i = 0; i < 16; ++i) {
        int r = i*4 + r4;
        t[r][c] = src[(size_t)(k0 + r) * NDM + n0 + c];
    }
    __syncthreads();
    #pragma unroll
    for (int i = 0; i < 16; ++i) {
        int n = i*4 + r4;
        dst[(size_t)(n0 + n) * NDM + k0 + c] = (f16)t[c][n];
    }
}

// ---------------------------------------------------------------------------
// Shared 128x128x(K=1024) f16 GEMM core, 256 thr (4 waves, each 64x64),
// BK=32, double-buffered LDS, reg-staged (2-barrier pattern).
// MODE 0: q = (acc+bq)*0.125*log2e -> [B,H,S,D] f16  (exp2 folding for attn)
// MODE 1: k = acc+bk         -> [B,H,S,D] f16
// MODE 2: v = acc+bv         -> [B,H,D,S] f16 (transposed for PV A-operand)
// MODE 3: out = acc+bo       -> [B,S,DM] f32 (d_out)
// ---------------------------------------------------------------------------
template<int MODE>
__device__ __forceinline__ void gemm128(const f16* __restrict__ A,
                                        const f16* __restrict__ Bw,
                                        const float* __restrict__ bias,
                                        void* __restrict__ outp,
                                        f16* __restrict__ AsB, f16* __restrict__ BsB)
{
    const int tid  = threadIdx.x;
    const int lane = tid & 63;
    const int wid  = tid >> 6;
    const int wr = wid >> 1, wc = wid & 1;
    const int m0 = blockIdx.y * 128, n0 = blockIdx.x * 128;
    const int K = 1024;

    // staging: thread covers 16B chunks {tid, tid+256}; row = c>>2, sub = (c&3)*8
    const int r0 = tid >> 2;
    const int s0 = (tid & 3) * 8;
    const f16* Arow0 = A  + (size_t)(m0 + r0)      * K + s0;
    const f16* Arow1 = A  + (size_t)(m0 + r0 + 64) * K + s0;
    const f16* Brow0 = Bw + (size_t)(n0 + r0)      * K + s0;
    const f16* Brow1 = Bw + (size_t)(n0 + r0 + 64) * K + s0;
    const int lds0 = r0*32 + s0;
    const int lds1 = (r0+64)*32 + s0;

    f16x8 ra0 = *(const f16x8*)(Arow0);
    f16x8 ra1 = *(const f16x8*)(Arow1);
    f16x8 rb0 = *(const f16x8*)(Brow0);
    f16x8 rb1 = *(const f16x8*)(Brow1);
    *(f16x8*)(AsB + lds0) = ra0; *(f16x8*)(AsB + lds1) = ra1;
    *(f16x8*)(BsB + lds0) = rb0; *(f16x8*)(BsB + lds1) = rb1;

    f32x4 acc[4][4];
    #pragma unroll
    for (int i = 0; i < 4; ++i)
        #pragma unroll
        for (int j = 0; j < 4; ++j) {
            f32x4 z4 = {0.f, 0.f, 0.f, 0.f};
            acc[i][j] = z4;
        }

    const int arow = wr*64 + (lane & 15);
    const int brow = wc*64 + (lane & 15);
    const int kc   = (lane >> 4) * 8;

    int cur = 0;
    for (int s = 0; s < 32; ++s) {
        const bool more = (s + 1 < 32);
        if (more) {   // issue next-tile global loads early; latency hides under MFMA
            const int kk = (s + 1) * 32;
            ra0 = *(const f16x8*)(Arow0 + kk); ra1 = *(const f16x8*)(Arow1 + kk);
            rb0 = *(const f16x8*)(Brow0 + kk); rb1 = *(const f16x8*)(Brow1 + kk);
        }
        __syncthreads();   // buf[cur] ds_writes visible
        {
            f16x8 af[4], bf[4];
            f16* Asc = AsB + cur*4096;
            f16* Bsc = BsB + cur*4096;
            #pragma unroll
            for (int rt = 0; rt < 4; ++rt) af[rt] = *(const f16x8*)(Asc + (arow + rt*16)*32 + kc);
            #pragma unroll
            for (int ct = 0; ct < 4; ++ct) bf[ct] = *(const f16x8*)(Bsc + (brow + ct*16)*32 + kc);
            #pragma unroll
            for (int rt = 0; rt < 4; ++rt)
                #pragma unroll
                for (int ct = 0; ct < 4; ++ct)
                    acc[rt][ct] = __builtin_amdgcn_mfma_f32_16x16x32_f16(af[rt], bf[ct], acc[rt][ct], 0, 0, 0);
        }
        __syncthreads();   // all reads of buf[cur^1] from prev iter done
        if (more) {
            f16* Asn = AsB + (cur^1)*4096;
            f16* Bsn = BsB + (cur^1)*4096;
            *(f16x8*)(Asn + lds0) = ra0; *(f16x8*)(Asn + lds1) = ra1;
            *(f16x8*)(Bsn + lds0) = rb0; *(f16x8*)(Bsn + lds1) = rb1;
        }
        cur ^= 1;
    }

    // epilogue: C[m][n], m = mb+j (row = (lane>>4)*4+j), n = tile base + (lane&15)
    #pragma unroll
    for (int rt = 0; rt < 4; ++rt) {
        const int mb = m0 + wr*64 + rt*16 + ((lane >> 4) << 2);
        #pragma unroll
        for (int ct = 0; ct < 4; ++ct) {
            const int n = n0 + wc*64 + ct*16 + (lane & 15);
            const float bn = bias[n];
            if (MODE == 0 || MODE == 1) {
                f16* dst = (f16*)outp;
                // MODE 0: fold 1/sqrt(D) AND log2(e) so attn can use exp2 directly
                const float sc = (MODE == 0) ? 0.125f * 1.44269504088896f : 1.0f;
                #pragma unroll
                for (int j = 0; j < 4; ++j) {
                    const int m = mb + j;
                    const float v = (acc[rt][ct][j] + bn) * sc;
                    // [B,H,S,D]: ((b*16+h)*2048+s)*64+d
                    dst[(size_t)((m >> 11)*16 + (n >> 6))*131072 + (size_t)(m & 2047)*64 + (n & 63)] = (f16)v;
                }
            } else if (MODE == 2) {
                f16* dst = (f16*)outp;
                f16x4 o;
                #pragma unroll
                for (int j = 0; j < 4; ++j) o[j] = (f16)(acc[rt][ct][j] + bn);
                // [B,H,D,S]: ((b*16+h)*64+d)*2048+s ; 4 consecutive s -> 8B store
                *(f16x4*)(dst + (size_t)((mb >> 11)*16 + (n >> 6))*131072 + (size_t)(n & 63)*2048 + (mb & 2047)) = o;
            } else {
                float* dst = (float*)outp;
                #pragma unroll
                for (int j = 0; j < 4; ++j) {
                    const int m = mb + j;
                    dst[(size_t)m * NDM + n] = acc[rt][ct][j] + bn;
                }
            }
        }
    }
}

// fused QKV projection: grid (8, 32, 3)
__global__ __launch_bounds__(256) void proj_kernel(const f16* __restrict__ xh, const f16* __restrict__ wt,
                                                   const float* __restrict__ bq, const float* __restrict__ bk,
                                                   const float* __restrict__ bv,
                                                   f16* __restrict__ qh, f16* __restrict__ kh, f16* __restrict__ vh)
{
    __shared__ f16 AsS[2*4096];
    __shared__ f16 BsS[2*4096];
    const int z = blockIdx.z;
    const f16* A  = xh + (size_t)z * ((size_t)NM * NDM);
    const f16* Bw = wt + (size_t)z * ((size_t)NDM * NDM);
    if (z == 0)      gemm128<0>(A, Bw, bq, qh, AsS, BsS);
    else if (z == 1) gemm128<1>(A, Bw, bk, kh, AsS, BsS);
    else             gemm128<2>(A, Bw, bv, vh, AsS, BsS);
}

// output projection: grid (8, 32)
__global__ __launch_bounds__(256) void outproj_kernel(const f16* __restrict__ ah, const f16* __restrict__ wto,
                                                      const float* __restrict__ bo, float* __restrict__ out)
{
    __shared__ f16 AsS[2*4096];
    __shared__ f16 BsS[2*4096];
    gemm128<3>(ah, wto, bo, out, AsS, BsS);
}

// ---------------------------------------------------------------------------
// K2: register-flash attention, 2-pass, zero LDS, zero barriers.
// Block = 512 thr (8 waves); each WAVE independently owns 16 q-rows x all 2048 k.
// Depth-slot permutation (sigma-trick): MFMA reduces over 32 depth slots; we map
// slot (g,e) -> kpos {4g+e | e<4 ; 16+4g+(e-4) | e>=4} on BOTH the P (B) and
// V (A) operands, so the QK output registers (pa from a, pc from b) feed PV
// directly -- no LDS roundtrip, no cross-lane shuffle.
// Software prefetch: tile t+1's K/V loads issue at loop top; nt-stores of the
// normalized f32 weights issue at loop bottom (younger stores can't block
// older load waits -> the 537MB weights write streams under compute).
// exp folded to exp2: q pre-scaled by 0.125*log2(e) in proj.
// grid: 512 = 8 XCD x (4 bh x 16 q-tiles); XCD swizzle keeps K/V in one L2.
// ---------------------------------------------------------------------------
__global__ __launch_bounds__(512, 4) void attn_kernel(const f16* __restrict__ qh,
                                                      const f16* __restrict__ kh,
                                                      const f16* __restrict__ vt,
                                                      f16* __restrict__ ah,
                                                      float* __restrict__ wout)
{
    const int tid  = threadIdx.x;
    const int lane = tid & 63;
    const int wid  = tid >> 6;
    const int l15  = lane & 15;
    const int g    = lane >> 4;

    // XCD swizzle: 4 bh per XCD, all 16 q-tile blocks of a bh on one XCD.
    const int xcd = blockIdx.x & 7;
    const int jj  = blockIdx.x >> 3;
    const int bh  = xcd * 4 + (jj & 3);
    const int qrow = (jj >> 2) * 128 + wid * 16 + l15;   // this lane's q-row

    const f16* qp = qh + ((size_t)bh * NS + qrow) * 64;
    const f16* kp2 = kh + (size_t)bh * NS * 64 + (size_t)l15 * 64 + g*8;
    const f16* vp2 = vt + (size_t)bh * 64 * NS + (size_t)l15 * NS + g*4;

    // Q fragments (B-operand: B[depth g*8+e][col l15=qrow])
    const f16x8 qf0 = *(const f16x8*)(qp + g*8);
    const f16x8 qf1 = *(const f16x8*)(qp + 32 + g*8);

    // ---- pass 1: rowsum of exp2(s') ----
    float rs = 0.f;
    {
        f16x8 cK0 = *(const f16x8*)(kp2);
        f16x8 cK1 = *(const f16x8*)(kp2 + 32);
        f16x8 cK2 = *(const f16x8*)(kp2 + 1024);
        f16x8 cK3 = *(const f16x8*)(kp2 + 1056);
        for (int t = 0; t < 64; ++t) {
            const int tn = (t + 1) & 63;     // &63: last prefetch wraps (in-bounds, unused)
            const f16* kt = kp2 + (size_t)tn * 2048;
            f16x8 nK0 = *(const f16x8*)(kt);
            f16x8 nK1 = *(const f16x8*)(kt + 32);
            f16x8 nK2 = *(const f16x8*)(kt + 1024);
            f16x8 nK3 = *(const f16x8*)(kt + 1056);
            f32x4 a = {0.f,0.f,0.f,0.f}, b = {0.f,0.f,0.f,0.f};
            a = __builtin_amdgcn_mfma_f32_16x16x32_f16(cK0, qf0, a, 0,0,0);
            a = __builtin_amdgcn_mfma_f32_16x16x32_f16(cK1, qf1, a, 0,0,0);
            b = __builtin_amdgcn_mfma_f32_16x16x32_f16(cK2, qf0, b, 0,0,0);
            b = __builtin_amdgcn_mfma_f32_16x16x32_f16(cK3, qf1, b, 0,0,0);
            #pragma unroll
            for (int u = 0; u < 4; ++u)
                rs += __builtin_amdgcn_exp2f(a[u]) + __builtin_amdgcn_exp2f(b[u]);
            cK0 = nK0; cK1 = nK1; cK2 = nK2; cK3 = nK3;
        }
    }
    // combine the 4 lane-groups holding the same q-row (width-64 wave)
    rs += __shfl_xor(rs, 16);
    rs += __shfl_xor(rs, 32);
    const float ri = 1.0f / rs;

    // ---- pass 2: weights write + PV (sigma-permuted depth slots) ----
    f32x4 acc0 = {0.f,0.f,0.f,0.f}, acc1 = acc0, acc2 = acc0, acc3 = acc0;
    float* wr = wout + ((size_t)bh * NS + qrow) * NS;

    f16x8 cK0 = *(const f16x8*)(kp2);
    f16x8 cK1 = *(const f16x8*)(kp2 + 32);
    f16x8 cK2 = *(const f16x8*)(kp2 + 1024);
    f16x8 cK3 = *(const f16x8*)(kp2 + 1056);
    f16x4 cV0 = *(const f16x4*)(vp2);
    f16x4 cV1 = *(const f16x4*)(vp2 + 16);
    f16x4 cV2 = *(const f16x4*)(vp2 + 16*NS);
    f16x4 cV3 = *(const f16x4*)(vp2 + 16*NS + 16);
    f16x4 cV4 = *(const f16x4*)(vp2 + 32*NS);
    f16x4 cV5 = *(const f16x4*)(vp2 + 32*NS + 16);
    f16x4 cV6 = *(const f16x4*)(vp2 + 48*NS);
    f16x4 cV7 = *(const f16x4*)(vp2 + 48*NS + 16);

    for (int t = 0; t < 64; ++t) {
        const int tn = (t + 1) & 63;
        // prefetch t+1 (K + V) -- issued before any dependent use or store
        const f16* kt = kp2 + (size_t)tn * 2048;
        f16x8 nK0 = *(const f16x8*)(kt);
        f16x8 nK1 = *(const f16x8*)(kt + 32);
        f16x8 nK2 = *(const f16x8*)(kt + 1024);
        f16x8 nK3 = *(const f16x8*)(kt + 1056);
        const f16* vtp = vp2 + tn*32;
        f16x4 nV0 = *(const f16x4*)(vtp);
        f16x4 nV1 = *(const f16x4*)(vtp + 16);
        f16x4 nV2 = *(const f16x4*)(vtp + 16*NS);
        f16x4 nV3 = *(const f16x4*)(vtp + 16*NS + 16);
        f16x4 nV4 = *(const f16x4*)(vtp + 32*NS);
        f16x4 nV5 = *(const f16x4*)(vtp + 32*NS + 16);
        f16x4 nV6 = *(const f16x4*)(vtp + 48*NS);
        f16x4 nV7 = *(const f16x4*)(vtp + 48*NS + 16);

        // QK^T: a -> kpos local {g*4+u}, b -> {16+g*4+u}
        f32x4 a = {0.f,0.f,0.f,0.f}, b = {0.f,0.f,0.f,0.f};
        a = __builtin_amdgcn_mfma_f32_16x16x32_f16(cK0, qf0, a, 0,0,0);
        a = __builtin_amdgcn_mfma_f32_16x16x32_f16(cK1, qf1, a, 0,0,0);
        b = __builtin_amdgcn_mfma_f32_16x16x32_f16(cK2, qf0, b, 0,0,0);
        b = __builtin_amdgcn_mfma_f32_16x16x32_f16(cK3, qf1, b, 0,0,0);

        f32x4 ea, eb; f16x4 pa, pc;
        #pragma unroll
        for (int u = 0; u < 4; ++u) {
            ea[u] = __builtin_amdgcn_exp2f(a[u]);
            eb[u] = __builtin_amdgcn_exp2f(b[u]);
            pa[u] = (f16)ea[u]; pc[u] = (f16)eb[u];
        }

        // PV with sigma-permuted slots: B-frag direct from registers
        f16x8 pf = __builtin_shufflevector(pa, pc, 0,1,2,3,4,5,6,7);
        f16x8 vA0 = __builtin_shufflevector(cV0, cV1, 0,1,2,3,4,5,6,7);
        f16x8 vA1 = __builtin_shufflevector(cV2, cV3, 0,1,2,3,4,5,6,7);
        f16x8 vA2 = __builtin_shufflevector(cV4, cV5, 0,1,2,3,4,5,6,7);
        f16x8 vA3 = __builtin_shufflevector(cV6, cV7, 0,1,2,3,4,5,6,7);
        acc0 = __builtin_amdgcn_mfma_f32_16x16x32_f16(vA0, pf, acc0, 0,0,0);
        acc1 = __builtin_amdgcn_mfma_f32_16x16x32_f16(vA1, pf, acc1, 0,0,0);
        acc2 = __builtin_amdgcn_mfma_f32_16x16x32_f16(vA2, pf, acc2, 0,0,0);
        acc3 = __builtin_amdgcn_mfma_f32_16x16x32_f16(vA3, pf, acc3, 0,0,0);

        // normalized f32 weights, nontemporal, issued last (youngest VMEM ops)
        f32x4 wa, wb;
        #pragma unroll
        for (int u = 0; u < 4; ++u) { wa[u] = ea[u]*ri; wb[u] = eb[u]*ri; }
        __builtin_nontemporal_store(wa, (f32x4*)(wr + t*32 + g*4));
        __builtin_nontemporal_store(wb, (f32x4*)(wr + t*32 + 16 + g*4));

        cK0 = nK0; cK1 = nK1; cK2 = nK2; cK3 = nK3;
        cV0 = nV0; cV1 = nV1; cV2 = nV2; cV3 = nV3;
        cV4 = nV4; cV5 = nV5; cV6 = nV6; cV7 = nV7;
    }

    // epilogue: lane holds out[qrow l15][d = dt*16 + g*4 + u]; normalize, f16x4 stores
    {
        const int bb = bh >> 4, hh = bh & 15;
        f16* arow = ah + ((size_t)(bb*NS + qrow)) * NDM + hh*64 + g*4;
        f16x4 o;
        #pragma unroll
        for (int u = 0; u < 4; ++u) o[u] = (f16)(acc0[u] * ri);
        *(f16x4*)(arow) = o;
        #pragma unroll
        for (int u = 0; u < 4; ++u) o[u] = (f16)(acc1[u] * ri);
        *(f16x4*)(arow + 16) = o;
        #pragma unroll
        for (int u = 0; u < 4; ++u) o[u] = (f16)(acc2[u] * ri);
        *(f16x4*)(arow + 32) = o;
        #pragma unroll
        for (int u = 0; u < 4; ++u) o[u] = (f16)(acc3[u] * ri);
        *(f16x4*)(arow + 48) = o;
    }
}

// ---------------------------------------------------------------------------
extern "C" void kernel_launch(void* const* d_in, const int* in_sizes, int n_in,
                              void* d_out, int out_size, void* d_ws, size_t ws_size,
                              hipStream_t stream)
{
    (void)in_sizes; (void)n_in; (void)out_size;
    const float* Q  = (const float*)d_in[0];
    const float* K  = (const float*)d_in[1];
    const float* V  = (const float*)d_in[2];
    const float* Wq = (const float*)d_in[3];
    const float* bq = (const float*)d_in[4];
    const float* Wk = (const float*)d_in[5];
    const float* bk = (const float*)d_in[6];
    const float* Wv = (const float*)d_in[7];
    const float* bv = (const float*)d_in[8];
    const float* Wo = (const float*)d_in[9];
    const float* bo = (const float*)d_in[10];

    if (ws_size < 67108864ull) return;  // need 64 MiB; abort -> stub-like absmax signals this

    f16* ws = (f16*)d_ws;
    f16* Xh = ws;                  // 3 x [4096][1024] f16 (Q,K,V inputs)
    f16* Wt = ws + 12582912;       // 4 x [1024][1024] f16 (W^T: q,k,v,o)
    f16* qh = ws + 16777216;       // [B,H,S,D] f16, pre-scaled by 0.125*log2e
    f16* kh = ws + 20971520;       // [B,H,S,D] f16
    f16* vt = ws + 25165824;       // [B,H,D,S] f16 (transposed)
    f16* ah = ws + 29360128;       // [B,S,DM] f16 (attn concat)
    float* out  = (float*)d_out;
    float* wout = out + 4194304;   // weights region

    cvt_x_kernel  <<<dim3(2048, 3, 1), dim3(256), 0, stream>>>(Q, K, V, Xh);
    transp_w_kernel<<<dim3(16, 16, 4), dim3(256), 0, stream>>>(Wq, Wk, Wv, Wo, Wt);
    proj_kernel   <<<dim3(8, 32, 3),  dim3(256), 0, stream>>>(Xh, Wt, bq, bk, bv, qh, kh, vt);
    attn_kernel   <<<dim3(512),       dim3(512), 0, stream>>>(qh, kh, vt, ah, wout);
    outproj_kernel<<<dim3(8, 32, 1),  dim3(256), 0, stream>>>(ah, Wt + 3*1048576, bo, out);
}

// Round 8
// 356.979 us; speedup vs baseline: 1.5530x; 1.5530x over previous
//
#include <hip/hip_runtime.h>
#include <hip/hip_fp16.h>
#include <stdint.h>
#include <stddef.h>

typedef _Float16 f16;
typedef _Float16 f16x8 __attribute__((ext_vector_type(8)));
typedef _Float16 f16x4 __attribute__((ext_vector_type(4)));
typedef float    f32x4 __attribute__((ext_vector_type(4)));

#define NB  2
#define NS  2048
#define NDM 1024
#define NH  16
#define ND  64
#define NM  4096   // NB*NS

// ---------------------------------------------------------------------------
// K0a: convert Q/K/V inputs f32 -> f16   (grid: (2048, 3), block 256; 8 elem/thr)
// ---------------------------------------------------------------------------
__global__ __launch_bounds__(256) void cvt_x_kernel(const float* __restrict__ q,
                                                    const float* __restrict__ k,
                                                    const float* __restrict__ v,
                                                    f16* __restrict__ xh)
{
    const float* src = (blockIdx.y == 0) ? q : (blockIdx.y == 1) ? k : v;
    f16* dst = xh + (size_t)blockIdx.y * ((size_t)NM * NDM);
    size_t i = ((size_t)blockIdx.x * 256 + threadIdx.x) * 8;
    float4 a = *(const float4*)(src + i);
    float4 b = *(const float4*)(src + i + 4);
    f16x8 o;
    o[0] = (f16)a.x; o[1] = (f16)a.y; o[2] = (f16)a.z; o[3] = (f16)a.w;
    o[4] = (f16)b.x; o[5] = (f16)b.y; o[6] = (f16)b.z; o[7] = (f16)b.w;
    *(f16x8*)(dst + i) = o;
}

// ---------------------------------------------------------------------------
// K0b: W [K][N] f32 -> Wt [N][K] f16 (transposed, so GEMM B-frags are contiguous)
// grid: (16,16,4), block 256, 64x64 tiles
// ---------------------------------------------------------------------------
__global__ __launch_bounds__(256) void transp_w_kernel(const float* __restrict__ w0,
                                                       const float* __restrict__ w1,
                                                       const float* __restrict__ w2,
                                                       const float* __restrict__ w3,
                                                       f16* __restrict__ wt)
{
    __shared__ float t[64][65];
    const int z = blockIdx.z;
    const float* src = (z==0)?w0:(z==1)?w1:(z==2)?w2:w3;
    f16* dst = wt + (size_t)z * ((size_t)NDM * NDM);
    const int k0 = blockIdx.y * 64, n0 = blockIdx.x * 64;
    const int c = threadIdx.x & 63, r4 = threadIdx.x >> 6;
    #pragma unroll
    for (int i = 0; i < 16; ++i) {
        int r = i*4 + r4;
        t[r][c] = src[(size_t)(k0 + r) * NDM + n0 + c];
    }
    __syncthreads();
    #pragma unroll
    for (int i = 0; i < 16; ++i) {
        int n = i*4 + r4;
        dst[(size_t)(n0 + n) * NDM + k0 + c] = (f16)t[c][n];
    }
}

// ---------------------------------------------------------------------------
// Shared 128x128x(K=1024) f16 GEMM core, 256 thr (4 waves, each 64x64),
// BK=32, double-buffered LDS, reg-staged (2-barrier pattern).
// MODE 0: q = (acc+bq)*0.125*log2e -> [B,H,S,D] f16  (exp2 folding for attn)
// MODE 1: k = acc+bk         -> [B,H,S,D] f16
// MODE 2: v = acc+bv         -> [B,H,D,S] f16 (transposed for PV A-operand)
// MODE 3: out = acc+bo       -> [B,S,DM] f32 (d_out)
// ---------------------------------------------------------------------------
template<int MODE>
__device__ __forceinline__ void gemm128(const f16* __restrict__ A,
                                        const f16* __restrict__ Bw,
                                        const float* __restrict__ bias,
                                        void* __restrict__ outp,
                                        f16* __restrict__ AsB, f16* __restrict__ BsB)
{
    const int tid  = threadIdx.x;
    const int lane = tid & 63;
    const int wid  = tid >> 6;
    const int wr = wid >> 1, wc = wid & 1;
    const int m0 = blockIdx.y * 128, n0 = blockIdx.x * 128;
    const int K = 1024;

    // staging: thread covers 16B chunks {tid, tid+256}; row = c>>2, sub = (c&3)*8
    const int r0 = tid >> 2;
    const int s0 = (tid & 3) * 8;
    const f16* Arow0 = A  + (size_t)(m0 + r0)      * K + s0;
    const f16* Arow1 = A  + (size_t)(m0 + r0 + 64) * K + s0;
    const f16* Brow0 = Bw + (size_t)(n0 + r0)      * K + s0;
    const f16* Brow1 = Bw + (size_t)(n0 + r0 + 64) * K + s0;
    const int lds0 = r0*32 + s0;
    const int lds1 = (r0+64)*32 + s0;

    f16x8 ra0 = *(const f16x8*)(Arow0);
    f16x8 ra1 = *(const f16x8*)(Arow1);
    f16x8 rb0 = *(const f16x8*)(Brow0);
    f16x8 rb1 = *(const f16x8*)(Brow1);
    *(f16x8*)(AsB + lds0) = ra0; *(f16x8*)(AsB + lds1) = ra1;
    *(f16x8*)(BsB + lds0) = rb0; *(f16x8*)(BsB + lds1) = rb1;

    f32x4 acc[4][4];
    #pragma unroll
    for (int i = 0; i < 4; ++i)
        #pragma unroll
        for (int j = 0; j < 4; ++j) {
            f32x4 z4 = {0.f, 0.f, 0.f, 0.f};
            acc[i][j] = z4;
        }

    const int arow = wr*64 + (lane & 15);
    const int brow = wc*64 + (lane & 15);
    const int kc   = (lane >> 4) * 8;

    int cur = 0;
    for (int s = 0; s < 32; ++s) {
        const bool more = (s + 1 < 32);
        if (more) {   // issue next-tile global loads early; latency hides under MFMA
            const int kk = (s + 1) * 32;
            ra0 = *(const f16x8*)(Arow0 + kk); ra1 = *(const f16x8*)(Arow1 + kk);
            rb0 = *(const f16x8*)(Brow0 + kk); rb1 = *(const f16x8*)(Brow1 + kk);
        }
        __syncthreads();   // buf[cur] ds_writes visible
        {
            f16x8 af[4], bf[4];
            f16* Asc = AsB + cur*4096;
            f16* Bsc = BsB + cur*4096;
            #pragma unroll
            for (int rt = 0; rt < 4; ++rt) af[rt] = *(const f16x8*)(Asc + (arow + rt*16)*32 + kc);
            #pragma unroll
            for (int ct = 0; ct < 4; ++ct) bf[ct] = *(const f16x8*)(Bsc + (brow + ct*16)*32 + kc);
            #pragma unroll
            for (int rt = 0; rt < 4; ++rt)
                #pragma unroll
                for (int ct = 0; ct < 4; ++ct)
                    acc[rt][ct] = __builtin_amdgcn_mfma_f32_16x16x32_f16(af[rt], bf[ct], acc[rt][ct], 0, 0, 0);
        }
        __syncthreads();   // all reads of buf[cur^1] from prev iter done
        if (more) {
            f16* Asn = AsB + (cur^1)*4096;
            f16* Bsn = BsB + (cur^1)*4096;
            *(f16x8*)(Asn + lds0) = ra0; *(f16x8*)(Asn + lds1) = ra1;
            *(f16x8*)(Bsn + lds0) = rb0; *(f16x8*)(Bsn + lds1) = rb1;
        }
        cur ^= 1;
    }

    // epilogue: C[m][n], m = mb+j (row = (lane>>4)*4+j), n = tile base + (lane&15)
    #pragma unroll
    for (int rt = 0; rt < 4; ++rt) {
        const int mb = m0 + wr*64 + rt*16 + ((lane >> 4) << 2);
        #pragma unroll
        for (int ct = 0; ct < 4; ++ct) {
            const int n = n0 + wc*64 + ct*16 + (lane & 15);
            const float bn = bias[n];
            if (MODE == 0 || MODE == 1) {
                f16* dst = (f16*)outp;
                // MODE 0: fold 1/sqrt(D) AND log2(e) so attn can use exp2 directly
                const float sc = (MODE == 0) ? 0.125f * 1.44269504088896f : 1.0f;
                #pragma unroll
                for (int j = 0; j < 4; ++j) {
                    const int m = mb + j;
                    const float v = (acc[rt][ct][j] + bn) * sc;
                    // [B,H,S,D]: ((b*16+h)*2048+s)*64+d
                    dst[(size_t)((m >> 11)*16 + (n >> 6))*131072 + (size_t)(m & 2047)*64 + (n & 63)] = (f16)v;
                }
            } else if (MODE == 2) {
                f16* dst = (f16*)outp;
                f16x4 o;
                #pragma unroll
                for (int j = 0; j < 4; ++j) o[j] = (f16)(acc[rt][ct][j] + bn);
                // [B,H,D,S]: ((b*16+h)*64+d)*2048+s ; 4 consecutive s -> 8B store
                *(f16x4*)(dst + (size_t)((mb >> 11)*16 + (n >> 6))*131072 + (size_t)(n & 63)*2048 + (mb & 2047)) = o;
            } else {
                float* dst = (float*)outp;
                #pragma unroll
                for (int j = 0; j < 4; ++j) {
                    const int m = mb + j;
                    dst[(size_t)m * NDM + n] = acc[rt][ct][j] + bn;
                }
            }
        }
    }
}

// fused QKV projection: grid (8, 32, 3)
__global__ __launch_bounds__(256) void proj_kernel(const f16* __restrict__ xh, const f16* __restrict__ wt,
                                                   const float* __restrict__ bq, const float* __restrict__ bk,
                                                   const float* __restrict__ bv,
                                                   f16* __restrict__ qh, f16* __restrict__ kh, f16* __restrict__ vh)
{
    __shared__ f16 AsS[2*4096];
    __shared__ f16 BsS[2*4096];
    const int z = blockIdx.z;
    const f16* A  = xh + (size_t)z * ((size_t)NM * NDM);
    const f16* Bw = wt + (size_t)z * ((size_t)NDM * NDM);
    if (z == 0)      gemm128<0>(A, Bw, bq, qh, AsS, BsS);
    else if (z == 1) gemm128<1>(A, Bw, bk, kh, AsS, BsS);
    else             gemm128<2>(A, Bw, bv, vh, AsS, BsS);
}

// output projection: grid (8, 32)
__global__ __launch_bounds__(256) void outproj_kernel(const f16* __restrict__ ah, const f16* __restrict__ wto,
                                                      const float* __restrict__ bo, float* __restrict__ out)
{
    __shared__ f16 AsS[2*4096];
    __shared__ f16 BsS[2*4096];
    gemm128<3>(ah, wto, bo, out, AsS, BsS);
}

// ---------------------------------------------------------------------------
// K2: fused attention with WAVE SPECIALIZATION in phase 2.
// 1 block = one (b,h) x 16 q-rows; 512 thr (8 waves).
// Phase 1 (all 8 waves): QK via swapped mfma(K,Q), exp2 (q pre-scaled by
//   0.125*log2e), P f16 -> st LDS, rowsum partials. One barrier.
// Phase 2 (split): waves 0-3 stream the normalized f32 weights (537 MB total)
//   from st via 256B-contiguous nt stores; waves 4-7 concurrently run PV
//   (each wave one 16-wide d-tile over the FULL k range -> no cross-wave
//   reduce, no scratch, no second barrier). Write BW overlaps MFMA.
// grid: 4096; XCD swizzle keeps each (b,h)'s 512 KB K/V in one XCD's L2.
// ---------------------------------------------------------------------------
__global__ __launch_bounds__(512) void attn_kernel(const f16* __restrict__ qh, const f16* __restrict__ kh,
                                                   const f16* __restrict__ vt, f16* __restrict__ ah,
                                                   float* __restrict__ wout)
{
    __shared__ f16   st[16 * 2056];   // [16 q-rows][2048 k (+8 pad)]
    __shared__ float redbuf[128];     // rowsum partials
    __shared__ float rinv[16];

    const int tid  = threadIdx.x;
    const int lane = tid & 63;
    const int wid  = tid >> 6;

    // XCD swizzle: 4 bh per XCD, all 128 q-tile blocks of a bh on one XCD.
    const int xcd   = blockIdx.x & 7;
    const int j     = blockIdx.x >> 3;
    const int bh    = xcd * 4 + (j & 3);
    const int qbase = (j >> 2) * 16;

    const f16* qp = qh + ((size_t)bh * NS + qbase) * 64;
    const f16* kp = kh + (size_t)bh * NS * 64;
    const f16* vp = vt + (size_t)bh * 64 * NS;

    const int l15 = lane & 15;
    const int g   = lane >> 4;        // 0..3

    // q fragments (B-operand): col = l15 (q row), depth = g*8 + e (+32)
    const f16x8 qf0 = *(const f16x8*)(qp + l15*64 + g*8);
    const f16x8 qf1 = *(const f16x8*)(qp + l15*64 + 32 + g*8);

    // ---- phase 1: QK -> exp2 -> st, rowsum ----
    float rs = 0.f;
    const f16* kbase = kp + (size_t)(wid*16 + l15) * 64 + g*8;
    f16* stw = st + l15*2056 + wid*16 + g*4;

    for (int t = 0; t < 16; ++t) {
        const f16* kb = kbase + (size_t)t * (128*64);
        f16x8 kf0 = *(const f16x8*)(kb);
        f16x8 kf1 = *(const f16x8*)(kb + 32);
        f32x4 a = {0.f, 0.f, 0.f, 0.f};
        a = __builtin_amdgcn_mfma_f32_16x16x32_f16(kf0, qf0, a, 0, 0, 0);
        a = __builtin_amdgcn_mfma_f32_16x16x32_f16(kf1, qf1, a, 0, 0, 0);
        // lane holds s[q-row = l15][k-col = t*128 + wid*16 + g*4 + u]
        f16x4 sv;
        #pragma unroll
        for (int u = 0; u < 4; ++u) {
            float e = __builtin_amdgcn_exp2f(a[u]);
            rs += e;
            sv[u] = (f16)e;
        }
        *(f16x4*)(stw + t*128) = sv;
    }

    // row sums: combine the 4 g-groups holding the same q-row, then across waves
    rs += __shfl_xor(rs, 16);
    rs += __shfl_xor(rs, 32);
    if (lane < 16) redbuf[wid*16 + lane] = rs;
    __syncthreads();
    if (tid < 16) {
        float sum = 0.f;
        #pragma unroll
        for (int w = 0; w < 8; ++w) sum += redbuf[w*16 + tid];
        rinv[tid] = 1.0f / sum;
    }
    __syncthreads();

    if (wid < 4) {
        // ---- phase 2a (waves 0-3): normalized weights -> d_out, nt f32x4 ----
        // wave covers rows wid*4+g (4 rows); 16 lanes x 16B = 256B runs per row
        const int r = wid*4 + g;
        const float ri = rinv[r];
        const f16x4* srow = (const f16x4*)(st + r*2056);
        float* orow = wout + ((size_t)bh * NS + qbase + r) * NS;
        #pragma unroll 8
        for (int i = 0; i < 32; ++i) {
            f16x4 sv = srow[l15 + i*16];
            f32x4 o;
            o[0] = (float)sv[0] * ri; o[1] = (float)sv[1] * ri;
            o[2] = (float)sv[2] * ri; o[3] = (float)sv[3] * ri;
            __builtin_nontemporal_store(o, (f32x4*)(orow + (size_t)(l15 + i*16)*4));
        }
    } else {
        // ---- phase 2b (waves 4-7): PV, one 16-wide d-tile per wave, full K ----
        const int nt = wid - 4;
        f32x4 acc = {0.f, 0.f, 0.f, 0.f};
        const f16* vb = vp + (size_t)(nt*16 + l15) * NS + g*8;   // A: V row = d
        const f16* sb = st + l15*2056 + g*8;                     // B: col = q row
        #pragma unroll 8
        for (int ks = 0; ks < 64; ++ks) {
            f16x8 vf = *(const f16x8*)(vb + ks*32);
            f16x8 sf = *(const f16x8*)(sb + ks*32);
            acc = __builtin_amdgcn_mfma_f32_16x16x32_f16(vf, sf, acc, 0, 0, 0);
        }
        // D: col = l15 = q, row = g*4+u = d within tile; 4 consecutive d -> 8B store
        const float ri = rinv[l15];
        const int bb = bh >> 4, hh = bh & 15;
        f16x4 o;
        #pragma unroll
        for (int u = 0; u < 4; ++u) o[u] = (f16)(acc[u] * ri);
        *(f16x4*)(ah + ((size_t)(bb*NS + qbase + l15)) * NDM + hh*64 + nt*16 + g*4) = o;
    }
}

// ---------------------------------------------------------------------------
extern "C" void kernel_launch(void* const* d_in, const int* in_sizes, int n_in,
                              void* d_out, int out_size, void* d_ws, size_t ws_size,
                              hipStream_t stream)
{
    (void)in_sizes; (void)n_in; (void)out_size;
    const float* Q  = (const float*)d_in[0];
    const float* K  = (const float*)d_in[1];
    const float* V  = (const float*)d_in[2];
    const float* Wq = (const float*)d_in[3];
    const float* bq = (const float*)d_in[4];
    const float* Wk = (const float*)d_in[5];
    const float* bk = (const float*)d_in[6];
    const float* Wv = (const float*)d_in[7];
    const float* bv = (const float*)d_in[8];
    const float* Wo = (const float*)d_in[9];
    const float* bo = (const float*)d_in[10];

    if (ws_size < 67108864ull) return;  // need 64 MiB; abort -> stub-like absmax signals this

    f16* ws = (f16*)d_ws;
    f16* Xh = ws;                  // 3 x [4096][1024] f16 (Q,K,V inputs)
    f16* Wt = ws + 12582912;       // 4 x [1024][1024] f16 (W^T: q,k,v,o)
    f16* qh = ws + 16777216;       // [B,H,S,D] f16, pre-scaled by 0.125*log2e
    f16* kh = ws + 20971520;       // [B,H,S,D] f16
    f16* vt = ws + 25165824;       // [B,H,D,S] f16 (transposed)
    f16* ah = ws + 29360128;       // [B,S,DM] f16 (attn concat)
    float* out  = (float*)d_out;
    float* wout = out + 4194304;   // weights region

    cvt_x_kernel  <<<dim3(2048, 3, 1), dim3(256), 0, stream>>>(Q, K, V, Xh);
    transp_w_kernel<<<dim3(16, 16, 4), dim3(256), 0, stream>>>(Wq, Wk, Wv, Wo, Wt);
    proj_kernel   <<<dim3(8, 32, 3),  dim3(256), 0, stream>>>(Xh, Wt, bq, bk, bv, qh, kh, vt);
    attn_kernel   <<<dim3(4096),      dim3(512), 0, stream>>>(qh, kh, vt, ah, wout);
    outproj_kernel<<<dim3(8, 32, 1),  dim3(256), 0, stream>>>(ah, Wt + 3*1048576, bo, out);
}